// Round 8
// baseline (160.027 us; speedup 1.0000x reference)
//
#include <hip/hip_runtime.h>
#include <math.h>

#define DEP   96
#define HEADS 96
#define BSZ   16
#define DIM   512
#define REL   128
#define RELP  129   // REL + nil

typedef __attribute__((ext_vector_type(8))) _Float16  half8;    // 8 fp16 (4 VGPRs)
typedef __attribute__((ext_vector_type(2))) __fp16    fp16x2;   // cvt_pkrtz return type
typedef __attribute__((ext_vector_type(4))) float     floatx4;

__device__ __forceinline__ unsigned short f2h(float x) {
    union { _Float16 h; unsigned short u; } c;
    c.h = (_Float16)x;                                   // v_cvt_f16_f32 (RNE)
    return c.u;
}
// two f32 -> packed 2xf16 in one v_cvt_pkrtz_f16_f32
__device__ __forceinline__ unsigned pk_f2h(float a, float b) {
    union { fp16x2 h; unsigned u; } c;
    c.h = __builtin_amdgcn_cvt_pkrtz(a, b);
    return c.u;
}
// packed fp16 add / relu (VOP3P)
__device__ __forceinline__ unsigned pk_add_h2(unsigned a, unsigned b) {
    unsigned r; asm("v_pk_add_f16 %0, %1, %2" : "=v"(r) : "v"(a), "v"(b)); return r;
}
__device__ __forceinline__ unsigned pk_max_h2(unsigned a, unsigned b) {
    unsigned r; asm("v_pk_max_f16 %0, %1, %2" : "=v"(r) : "v"(a), "v"(b)); return r;
}

#define PSS 72   // proj LDS row stride (fp16 elems): 144 B, 16B-aligned rows

// ---------------------------------------------------------------------------
// Kernel A: projections via fp16 MFMA (R5 shape — 32x64 tiles, 768 blocks,
// 3 resident/CU; measured healthy, unchanged).
//   z=0: P1[m][n] = outs@Wt[:, :512]^T + bt   (f32 out)
//   z=1: P2H[m][n]= graph@Wt[:, 512:]^T       (fp16 out)
// First 32 blocks also cast Wp -> WpH as a prelude.
// ---------------------------------------------------------------------------
__global__ __launch_bounds__(256) void proj_kernel(
    const float* __restrict__ outs, const float* __restrict__ graph,
    const float* __restrict__ Wt, const float* __restrict__ bt,
    const float* __restrict__ Wp,
    float* __restrict__ P1, unsigned short* __restrict__ P2H,
    unsigned short* __restrict__ WpH)
{
    // ---- Wp f32 -> fp16 prelude: 32 blocks x 256 thr ----
    {
        const int fb = (blockIdx.z * gridDim.y + blockIdx.y) * gridDim.x + blockIdx.x;
        if (fb < 32) {
            const int c = fb * 256 + (int)threadIdx.x;       // 0..8191 chunks of 8
            float4 a = *(const float4*)(Wp + (size_t)c * 8);
            float4 b = *(const float4*)(Wp + (size_t)c * 8 + 4);
            uint4 o;
            o.x = pk_f2h(a.x, a.y); o.y = pk_f2h(a.z, a.w);
            o.z = pk_f2h(b.x, b.y); o.w = pk_f2h(b.z, b.w);
            *(uint4*)(WpH + (size_t)c * 8) = o;
        }
    }

    const int z = blockIdx.z;
    const float* A = z ? graph : outs;
    const int off  = z ? DIM : 0;
    const int row0 = blockIdx.y * 32;
    const int col0 = blockIdx.x * 64;

    __shared__ __align__(16) unsigned short As[32 * PSS];   // [m][k] fp16
    __shared__ __align__(16) unsigned short Ws[64 * PSS];   // [n][k] fp16

    const int tid  = threadIdx.x;
    const int lane = tid & 63;
    const int wv   = tid >> 6;          // 0..3
    const int ln15 = lane & 15;
    const int quad = lane >> 4;
    const int mh   = wv & 1;            // m-half: rows [16*mh, 16*mh+16)
    const int nh   = wv >> 1;           // n-half: cols [32*nh, 32*nh+32)

    floatx4 acc[2];
    acc[0] = (floatx4){0.f,0.f,0.f,0.f};
    acc[1] = (floatx4){0.f,0.f,0.f,0.f};

    for (int kt = 0; kt < DIM; kt += 64) {
        // A: f32 load + packed RTZ cast to fp16 LDS (1 slot/thread)
        {
            const int r  = tid >> 3;            // 0..31
            const int e8 = (tid & 7) * 8;
            const float* p = A + (size_t)(row0 + r) * DIM + kt + e8;
            float4 va = *(const float4*)p;
            float4 vb = *(const float4*)(p + 4);
            uint4 o;
            o.x = pk_f2h(va.x, va.y); o.y = pk_f2h(va.z, va.w);
            o.z = pk_f2h(vb.x, vb.y); o.w = pk_f2h(vb.z, vb.w);
            *(uint4*)&As[r * PSS + e8] = o;
        }
        // Wt: f32 load + cast (2 slots/thread)
        #pragma unroll
        for (int q = 0; q < 2; ++q) {
            const int slot = q*256 + tid;       // 0..511
            const int r  = slot >> 3;           // 0..63
            const int e8 = (slot & 7) * 8;
            const float* p = Wt + (size_t)(col0 + r) * (2*DIM) + off + kt + e8;
            float4 va = *(const float4*)p;
            float4 vb = *(const float4*)(p + 4);
            uint4 o;
            o.x = pk_f2h(va.x, va.y); o.y = pk_f2h(va.z, va.w);
            o.z = pk_f2h(vb.x, vb.y); o.w = pk_f2h(vb.z, vb.w);
            *(uint4*)&Ws[r * PSS + e8] = o;
        }
        __syncthreads();
        #pragma unroll
        for (int ks = 0; ks < 64; ks += 32) {
            half8 af = *(const half8*)&As[(mh*16 + ln15) * PSS + ks + quad*8];
            #pragma unroll
            for (int nt = 0; nt < 2; ++nt) {
                half8 bf8 = *(const half8*)&Ws[(nh*32 + nt*16 + ln15) * PSS + ks + quad*8];
                acc[nt] = __builtin_amdgcn_mfma_f32_16x16x32_f16(af, bf8, acc[nt], 0, 0, 0);
            }
        }
        __syncthreads();
    }

    #pragma unroll
    for (int nt = 0; nt < 2; ++nt) {
        #pragma unroll
        for (int reg = 0; reg < 4; ++reg) {
            const int m = row0 + mh*16 + quad*4 + reg;
            const int n = col0 + nh*32 + nt*16 + ln15;
            float v = acc[nt][reg];
            if (!z) P1[(size_t)m * DIM + n] = v + bt[n];
            else    P2H[(size_t)m * DIM + n] = f2h(v);
        }
    }
}

// ---------------------------------------------------------------------------
// Kernel B: fused pairwise relu + fp16-MFMA GEMM + log_softmax(129).
// R8: R4's exact compute structure (padded PSS-72 tiles, __syncthreads,
// launch_bounds(256,4) — every compiler-visible cap tried in R2/R6/R7 hurt
// codegen more than it helped occupancy). LDS shaved 35.3 -> 31.5 KB to fit
// the 5th resident block/CU (20 waves, was 16) WITHOUT touching codegen:
//   1. drowH LDS eliminated — each thread's dep-row addend dv is a fixed
//      32 B P1 slice, loaded per kt from L2 in parallel with the pv/ws
//      loads that already wait there (same values, same cast: bit-identical).
//   2. pmx/pl/lseS overlaid into the arena after outb (epilogue-only).
// LDS = 32256 B arena only -> 5 blocks/CU at VGPR ~60 (5 waves/SIMD x 60
// = 300 <= 512-reg pool).
// ---------------------------------------------------------------------------
#define HSS 72
#define WSS 72

__global__ __launch_bounds__(256, 4) void fused_kernel(
    const float* __restrict__ P1, const unsigned short* __restrict__ P2H,
    const unsigned short* __restrict__ WpH, const float* __restrict__ bp,
    float* __restrict__ out)
{
    const int db = blockIdx.x;      // d*16 + b
    const int b  = db & 15;

    // K-loop: hs[96][72] @0 (13824) | ws[128][72] @13824 (18432) = 32256 B
    // epilogue overlay: outb[48*129] f32 @0 (24768) | pmx @24768 | pl | lseS
    __shared__ __align__(16) char arena[96*HSS*2 + 128*WSS*2];
    unsigned short* hs = (unsigned short*)arena;               // h tile  [m][k]
    unsigned short* ws = (unsigned short*)(arena + 96*HSS*2);  // Wp tile [n][k]
    float* outb = (float*)arena;                               // [48*129] epilogue
    float* pmx  = (float*)(arena + 24768);                     // [96][2]
    float* pl   = pmx + 192;                                   // [96][2]
    float* lseS = pl + 192;                                    // [96]

    const int tid  = threadIdx.x;       // 0..255
    const int lane = tid & 63;
    const int wv   = tid >> 6;          // 0..3
    const int ln15 = lane & 15;
    const int quad = lane >> 4;
    const int mh   = wv & 1;            // row half: [48*mh, 48*mh+48)
    const int nh   = wv >> 1;           // col half: [64*nh, 64*nh+64)
    const int e8   = (tid & 7) * 8;     // k-slot (elems), fixed per thread

    const float* drow = P1 + (size_t)db * DIM;   // this block's dep row (f32)

    floatx4 acc[3][4];
    #pragma unroll
    for (int i = 0; i < 3; ++i)
        #pragma unroll
        for (int j = 0; j < 4; ++j) acc[i][j] = (floatx4){0.f,0.f,0.f,0.f};

    for (int kt = 0; kt < DIM; kt += 64) {
        // ---- dv: per-thread dep-row addend, straight from L2 (no LDS) ----
        float4 d0 = *(const float4*)(drow + kt + e8);
        float4 d1 = *(const float4*)(drow + kt + e8 + 4);
        uint4 dv;
        dv.x = pk_f2h(d0.x, d0.y); dv.y = pk_f2h(d0.z, d0.w);
        dv.z = pk_f2h(d1.x, d1.y); dv.w = pk_f2h(d1.z, d1.w);

        // ---- stage hs[h][e] = fp16 relu(drow[e] + P2H[h,b,e]), 96x64 ----
        // slot&7 == tid&7 for all q, so dv matches every slot this thread writes
        #pragma unroll
        for (int q = 0; q < 3; ++q) {
            const int h = (q*256 + tid) >> 3;    // 0..95
            uint4 pv = *(const uint4*)(P2H + ((size_t)h * BSZ + b) * DIM + kt + e8);
            uint4 o;
            o.x = pk_max_h2(pk_add_h2(pv.x, dv.x), 0u);
            o.y = pk_max_h2(pk_add_h2(pv.y, dv.y), 0u);
            o.z = pk_max_h2(pk_add_h2(pv.z, dv.z), 0u);
            o.w = pk_max_h2(pk_add_h2(pv.w, dv.w), 0u);
            *(uint4*)&hs[h * HSS + e8] = o;
        }
        // ---- stage ws[r][e] = WpH[r][kt+e], 128x64 (B-operand layout) ----
        #pragma unroll
        for (int q = 0; q < 4; ++q) {
            const int r = (q*256 + tid) >> 3;    // 0..127
            *(uint4*)&ws[r * WSS + e8] =
                *(const uint4*)(WpH + (size_t)r * DIM + kt + e8);
        }
        __syncthreads();

        #pragma unroll
        for (int ks = 0; ks < 64; ks += 32) {
            half8 af[3], bf[4];
            #pragma unroll
            for (int mt = 0; mt < 3; ++mt)
                af[mt] = *(const half8*)&hs[(mh*48 + mt*16 + ln15) * HSS + ks + quad*8];
            #pragma unroll
            for (int nt = 0; nt < 4; ++nt)
                bf[nt] = *(const half8*)&ws[(nh*64 + nt*16 + ln15) * WSS + ks + quad*8];
            #pragma unroll
            for (int nt = 0; nt < 4; ++nt)
                #pragma unroll
                for (int mt = 0; mt < 3; ++mt)
                    acc[mt][nt] = __builtin_amdgcn_mfma_f32_16x16x32_f16(
                        af[mt], bf[nt], acc[mt][nt], 0, 0, 0);
        }
        __syncthreads();
    }

    // ---- epilogue phase 1: per-quadrant softmax partials (no nil yet) ----
    float bpv[4];
    #pragma unroll
    for (int nt = 0; nt < 4; ++nt) bpv[nt] = bp[nh*64 + nt*16 + ln15];

    #pragma unroll
    for (int mt = 0; mt < 3; ++mt) {
        #pragma unroll
        for (int reg = 0; reg < 4; ++reg) {
            const int m = mh*48 + mt*16 + quad*4 + reg;
            float s[4];
            #pragma unroll
            for (int nt = 0; nt < 4; ++nt) s[nt] = acc[mt][nt][reg] + bpv[nt];
            float mx = fmaxf(fmaxf(s[0], s[1]), fmaxf(s[2], s[3]));
            #pragma unroll
            for (int msk = 1; msk < 16; msk <<= 1) mx = fmaxf(mx, __shfl_xor(mx, msk));
            float l = 0.f;
            #pragma unroll
            for (int nt = 0; nt < 4; ++nt) l += __expf(s[nt] - mx);
            #pragma unroll
            for (int msk = 1; msk < 16; msk <<= 1) l += __shfl_xor(l, msk);
            if (ln15 == 0) { pmx[m*2 + nh] = mx; pl[m*2 + nh] = l; }
        }
    }
    __syncthreads();

    // ---- phase 1.5: lse once per row ----
    if (tid < 96) {
        const float mx0 = pmx[tid*2], mx1 = pmx[tid*2 + 1];
        const float MX = fmaxf(fmaxf(mx0, mx1), 0.f);   // nil = 0 in max
        const float L  = pl[tid*2] * __expf(mx0 - MX) + pl[tid*2 + 1] * __expf(mx1 - MX)
                       + __expf(-MX);                    // nil term
        lseS[tid] = MX + __logf(L);
    }
    __syncthreads();

    // ---- phase 2: stage each 48-row half in LDS, stream out coalesced ----
    #pragma unroll
    for (int g = 0; g < 2; ++g) {
        if (mh == g) {
            #pragma unroll
            for (int mt = 0; mt < 3; ++mt) {
                #pragma unroll
                for (int reg = 0; reg < 4; ++reg) {
                    const int lrow = mt*16 + quad*4 + reg;      // 0..47
                    const float lse = lseS[g*48 + lrow];
                    #pragma unroll
                    for (int nt = 0; nt < 4; ++nt)
                        outb[lrow*RELP + 1 + nh*64 + nt*16 + ln15] =
                            acc[mt][nt][reg] + bpv[nt] - lse;
                    if (nh == 0 && ln15 == 0) outb[lrow*RELP] = -lse;
                }
            }
        }
        __syncthreads();
        // 48*129 = 6192 floats = 1548 float4, contiguous in out
        float4* gout = (float4*)(out + (size_t)db * (HEADS*RELP) + g * (48*RELP));
        const float4* lsrc = (const float4*)outb;
        for (int j = tid; j < 1548; j += 256)
            gout[j] = lsrc[j];
        __syncthreads();
    }
}

extern "C" void kernel_launch(void* const* d_in, const int* in_sizes, int n_in,
                              void* d_out, int out_size, void* d_ws, size_t ws_size,
                              hipStream_t stream) {
    const float* outs  = (const float*)d_in[0];
    const float* graph = (const float*)d_in[1];
    const float* Wt    = (const float*)d_in[2];
    const float* bt    = (const float*)d_in[3];
    const float* Wp    = (const float*)d_in[4];
    const float* bp    = (const float*)d_in[5];
    float* out = (float*)d_out;

    // Workspace: 4,849,664 B (WtH eliminated; Wt cast inline in proj).
    float* P1           = (float*)d_ws;                     // [1536][512] f32   (3 MB)
    unsigned short* P2H = (unsigned short*)(P1 + 786432);   // [1536][512] fp16  (1.5 MB)
    unsigned short* WpH = P2H + 786432;                     // [128][512]  fp16  (128 KB)

    proj_kernel<<<dim3(DIM/64, (DEP*BSZ)/32, 2), 256, 0, stream>>>(
        outs, graph, Wt, bt, Wp, P1, P2H, WpH);
    fused_kernel<<<DEP*BSZ, 256, 0, stream>>>(P1, P2H, WpH, bp, out);
}

// Round 9
// 151.264 us; speedup vs baseline: 1.0579x; 1.0579x over previous
//
#include <hip/hip_runtime.h>
#include <math.h>

#define DEP   96
#define HEADS 96
#define BSZ   16
#define DIM   512
#define REL   128
#define RELP  129   // REL + nil

typedef __attribute__((ext_vector_type(8))) _Float16  half8;    // 8 fp16 (4 VGPRs)
typedef __attribute__((ext_vector_type(2))) __fp16    fp16x2;   // cvt_pkrtz return type
typedef __attribute__((ext_vector_type(4))) float     floatx4;

__device__ __forceinline__ unsigned short f2h(float x) {
    union { _Float16 h; unsigned short u; } c;
    c.h = (_Float16)x;                                   // v_cvt_f16_f32 (RNE)
    return c.u;
}
// two f32 -> packed 2xf16 in one v_cvt_pkrtz_f16_f32
__device__ __forceinline__ unsigned pk_f2h(float a, float b) {
    union { fp16x2 h; unsigned u; } c;
    c.h = __builtin_amdgcn_cvt_pkrtz(a, b);
    return c.u;
}
// packed fp16 add / relu (VOP3P)
__device__ __forceinline__ unsigned pk_add_h2(unsigned a, unsigned b) {
    unsigned r; asm("v_pk_add_f16 %0, %1, %2" : "=v"(r) : "v"(a), "v"(b)); return r;
}
__device__ __forceinline__ unsigned pk_max_h2(unsigned a, unsigned b) {
    unsigned r; asm("v_pk_max_f16 %0, %1, %2" : "=v"(r) : "v"(a), "v"(b)); return r;
}

#define PSS 72   // proj LDS row stride (fp16 elems): 144 B, 16B-aligned rows

// ---------------------------------------------------------------------------
// Kernel A: projections via fp16 MFMA (R5 shape — unchanged, measured healthy).
//   z=0: P1[m][n] = outs@Wt[:, :512]^T + bt   (f32 out)
//   z=1: P2H[m][n]= graph@Wt[:, 512:]^T       (fp16 out)
// First 32 blocks also cast Wp -> WpH as a prelude.
// ---------------------------------------------------------------------------
__global__ __launch_bounds__(256) void proj_kernel(
    const float* __restrict__ outs, const float* __restrict__ graph,
    const float* __restrict__ Wt, const float* __restrict__ bt,
    const float* __restrict__ Wp,
    float* __restrict__ P1, unsigned short* __restrict__ P2H,
    unsigned short* __restrict__ WpH)
{
    // ---- Wp f32 -> fp16 prelude: 32 blocks x 256 thr ----
    {
        const int fb = (blockIdx.z * gridDim.y + blockIdx.y) * gridDim.x + blockIdx.x;
        if (fb < 32) {
            const int c = fb * 256 + (int)threadIdx.x;       // 0..8191 chunks of 8
            float4 a = *(const float4*)(Wp + (size_t)c * 8);
            float4 b = *(const float4*)(Wp + (size_t)c * 8 + 4);
            uint4 o;
            o.x = pk_f2h(a.x, a.y); o.y = pk_f2h(a.z, a.w);
            o.z = pk_f2h(b.x, b.y); o.w = pk_f2h(b.z, b.w);
            *(uint4*)(WpH + (size_t)c * 8) = o;
        }
    }

    const int z = blockIdx.z;
    const float* A = z ? graph : outs;
    const int off  = z ? DIM : 0;
    const int row0 = blockIdx.y * 32;
    const int col0 = blockIdx.x * 64;

    __shared__ __align__(16) unsigned short As[32 * PSS];   // [m][k] fp16
    __shared__ __align__(16) unsigned short Ws[64 * PSS];   // [n][k] fp16

    const int tid  = threadIdx.x;
    const int lane = tid & 63;
    const int wv   = tid >> 6;          // 0..3
    const int ln15 = lane & 15;
    const int quad = lane >> 4;
    const int mh   = wv & 1;            // m-half: rows [16*mh, 16*mh+16)
    const int nh   = wv >> 1;           // n-half: cols [32*nh, 32*nh+32)

    floatx4 acc[2];
    acc[0] = (floatx4){0.f,0.f,0.f,0.f};
    acc[1] = (floatx4){0.f,0.f,0.f,0.f};

    for (int kt = 0; kt < DIM; kt += 64) {
        // A: f32 load + packed RTZ cast to fp16 LDS (1 slot/thread)
        {
            const int r  = tid >> 3;            // 0..31
            const int e8 = (tid & 7) * 8;
            const float* p = A + (size_t)(row0 + r) * DIM + kt + e8;
            float4 va = *(const float4*)p;
            float4 vb = *(const float4*)(p + 4);
            uint4 o;
            o.x = pk_f2h(va.x, va.y); o.y = pk_f2h(va.z, va.w);
            o.z = pk_f2h(vb.x, vb.y); o.w = pk_f2h(vb.z, vb.w);
            *(uint4*)&As[r * PSS + e8] = o;
        }
        // Wt: f32 load + cast (2 slots/thread)
        #pragma unroll
        for (int q = 0; q < 2; ++q) {
            const int slot = q*256 + tid;       // 0..511
            const int r  = slot >> 3;           // 0..63
            const int e8 = (slot & 7) * 8;
            const float* p = Wt + (size_t)(col0 + r) * (2*DIM) + off + kt + e8;
            float4 va = *(const float4*)p;
            float4 vb = *(const float4*)(p + 4);
            uint4 o;
            o.x = pk_f2h(va.x, va.y); o.y = pk_f2h(va.z, va.w);
            o.z = pk_f2h(vb.x, vb.y); o.w = pk_f2h(vb.z, vb.w);
            *(uint4*)&Ws[r * PSS + e8] = o;
        }
        __syncthreads();
        #pragma unroll
        for (int ks = 0; ks < 64; ks += 32) {
            half8 af = *(const half8*)&As[(mh*16 + ln15) * PSS + ks + quad*8];
            #pragma unroll
            for (int nt = 0; nt < 2; ++nt) {
                half8 bf8 = *(const half8*)&Ws[(nh*32 + nt*16 + ln15) * PSS + ks + quad*8];
                acc[nt] = __builtin_amdgcn_mfma_f32_16x16x32_f16(af, bf8, acc[nt], 0, 0, 0);
            }
        }
        __syncthreads();
    }

    #pragma unroll
    for (int nt = 0; nt < 2; ++nt) {
        #pragma unroll
        for (int reg = 0; reg < 4; ++reg) {
            const int m = row0 + mh*16 + quad*4 + reg;
            const int n = col0 + nh*32 + nt*16 + ln15;
            float v = acc[nt][reg];
            if (!z) P1[(size_t)m * DIM + n] = v + bt[n];
            else    P2H[(size_t)m * DIM + n] = f2h(v);
        }
    }
}

// ---------------------------------------------------------------------------
// Kernel B: fused pairwise relu + fp16-MFMA GEMM + log_softmax(129).
// R9: BK 64 -> 32. Pure geometry change: LDS 32.3 -> 18.9 KB so ALL 6
// blocks/CU are resident at once (24 waves/CU, 75% cap, no 4-then-2 tail).
// No compiler-visible caps (launch_bounds stays (256,4); R2/R6/R7/R8 all
// showed caps/codegen perturbation regress). dv comes from drowH LDS as in
// R4 (R8's global reload regressed). Stride-40 rows: 80 B = 16B-aligned,
// 2-way banks (free). Per kt: 12 MFMA/wave, 2 barriers, 16 kts.
// Issue-work arithmetic: ~8.6 us of issue per CU vs 48 us measured => 80%
// stall; 6 resident contexts (was 4 - tail) is the latency-hiding fix.
// Epilogue: direct stores (R4 staged version measured neutral) +
// lse-once-per-row; partials overlay the dead hs region.
// ---------------------------------------------------------------------------
#define HS2 40   // hs/ws row stride (fp16): 80 B, 16B-aligned

__global__ __launch_bounds__(256, 4) void fused_kernel(
    const float* __restrict__ P1, const unsigned short* __restrict__ P2H,
    const unsigned short* __restrict__ WpH, const float* __restrict__ bp,
    float* __restrict__ out)
{
    const int db = blockIdx.x;      // d*16 + b
    const int b  = db & 15;

    // K-loop: hs[96][40] @0 (7680) | ws[128][40] @7680 (10240) |
    //         drowH[512] @17920 (1024)  -> total 18944 B
    // epilogue overlay (hs dead): pmx[96][2] @0 | pl[96][2] | lseS[96]
    __shared__ __align__(16) char arena[18944];
    unsigned short* hs    = (unsigned short*)arena;            // [96][40]
    unsigned short* ws    = (unsigned short*)(arena + 7680);   // [128][40]
    unsigned short* drowH = (unsigned short*)(arena + 17920);  // [512]
    float* pmx  = (float*)arena;                               // [96][2]
    float* pl   = pmx + 192;                                   // [96][2]
    float* lseS = pl + 192;                                    // [96]

    const int tid  = threadIdx.x;       // 0..255
    const int lane = tid & 63;
    const int wv   = tid >> 6;          // 0..3
    const int ln15 = lane & 15;
    const int quad = lane >> 4;
    const int mh   = wv & 1;            // row half: [48*mh, 48*mh+48)
    const int nh   = wv >> 1;           // col half: [64*nh, 64*nh+64)
    const int e8   = (tid & 3) * 8;     // k-slot within BK=32, fixed per thread
    const int r0   = tid >> 2;          // 0..63

    // dep row f32 -> fp16 (one-time)
    {
        float2 v = *(const float2*)(P1 + (size_t)db * DIM + tid*2);
        *(unsigned*)&drowH[tid*2] = pk_f2h(v.x, v.y);
    }
    __syncthreads();

    floatx4 acc[3][4];
    #pragma unroll
    for (int i = 0; i < 3; ++i)
        #pragma unroll
        for (int j = 0; j < 4; ++j) acc[i][j] = (floatx4){0.f,0.f,0.f,0.f};

    for (int kt = 0; kt < DIM; kt += 32) {
        uint4 dv = *(const uint4*)&drowH[kt + e8];
        // ---- stage hs[h][e] = fp16 relu(drow[e] + P2H[h,b,e]), 96x32 ----
        {
            const int h = r0;                    // rows 0..63 (all threads)
            uint4 pv = *(const uint4*)(P2H + ((size_t)h * BSZ + b) * DIM + kt + e8);
            uint4 o;
            o.x = pk_max_h2(pk_add_h2(pv.x, dv.x), 0u);
            o.y = pk_max_h2(pk_add_h2(pv.y, dv.y), 0u);
            o.z = pk_max_h2(pk_add_h2(pv.z, dv.z), 0u);
            o.w = pk_max_h2(pk_add_h2(pv.w, dv.w), 0u);
            *(uint4*)&hs[h * HS2 + e8] = o;
        }
        if (tid < 128) {                         // rows 64..95 (waves 0-1)
            const int h = 64 + r0;
            uint4 pv = *(const uint4*)(P2H + ((size_t)h * BSZ + b) * DIM + kt + e8);
            uint4 o;
            o.x = pk_max_h2(pk_add_h2(pv.x, dv.x), 0u);
            o.y = pk_max_h2(pk_add_h2(pv.y, dv.y), 0u);
            o.z = pk_max_h2(pk_add_h2(pv.z, dv.z), 0u);
            o.w = pk_max_h2(pk_add_h2(pv.w, dv.w), 0u);
            *(uint4*)&hs[h * HS2 + e8] = o;
        }
        // ---- stage ws[r][e] = WpH[r][kt+e], 128x32 (2 slots/thread) ----
        #pragma unroll
        for (int q = 0; q < 2; ++q) {
            const int r = q*64 + r0;             // 0..127
            *(uint4*)&ws[r * HS2 + e8] =
                *(const uint4*)(WpH + (size_t)r * DIM + kt + e8);
        }
        __syncthreads();

        // ---- single K-step: 12 MFMA/wave ----
        {
            half8 af[3], bf[4];
            #pragma unroll
            for (int mt = 0; mt < 3; ++mt)
                af[mt] = *(const half8*)&hs[(mh*48 + mt*16 + ln15) * HS2 + quad*8];
            #pragma unroll
            for (int nt = 0; nt < 4; ++nt)
                bf[nt] = *(const half8*)&ws[(nh*64 + nt*16 + ln15) * HS2 + quad*8];
            #pragma unroll
            for (int nt = 0; nt < 4; ++nt)
                #pragma unroll
                for (int mt = 0; mt < 3; ++mt)
                    acc[mt][nt] = __builtin_amdgcn_mfma_f32_16x16x32_f16(
                        af[mt], bf[nt], acc[mt][nt], 0, 0, 0);
        }
        __syncthreads();
    }

    // ---- epilogue phase 1: per-quadrant softmax partials (no nil yet) ----
    float bpv[4];
    #pragma unroll
    for (int nt = 0; nt < 4; ++nt) bpv[nt] = bp[nh*64 + nt*16 + ln15];

    #pragma unroll
    for (int mt = 0; mt < 3; ++mt) {
        #pragma unroll
        for (int reg = 0; reg < 4; ++reg) {
            const int m = mh*48 + mt*16 + quad*4 + reg;
            float s[4];
            #pragma unroll
            for (int nt = 0; nt < 4; ++nt) s[nt] = acc[mt][nt][reg] + bpv[nt];
            float mx = fmaxf(fmaxf(s[0], s[1]), fmaxf(s[2], s[3]));
            #pragma unroll
            for (int msk = 1; msk < 16; msk <<= 1) mx = fmaxf(mx, __shfl_xor(mx, msk));
            float l = 0.f;
            #pragma unroll
            for (int nt = 0; nt < 4; ++nt) l += __expf(s[nt] - mx);
            #pragma unroll
            for (int msk = 1; msk < 16; msk <<= 1) l += __shfl_xor(l, msk);
            if (ln15 == 0) { pmx[m*2 + nh] = mx; pl[m*2 + nh] = l; }
        }
    }
    __syncthreads();

    // ---- phase 1.5: lse once per row ----
    if (tid < 96) {
        const float mx0 = pmx[tid*2], mx1 = pmx[tid*2 + 1];
        const float MX = fmaxf(fmaxf(mx0, mx1), 0.f);   // nil = 0 in max
        const float L  = pl[tid*2] * __expf(mx0 - MX) + pl[tid*2 + 1] * __expf(mx1 - MX)
                       + __expf(-MX);                    // nil term
        lseS[tid] = MX + __logf(L);
    }
    __syncthreads();

    // ---- phase 2: direct stores (staged variant measured neutral in R4) ----
    #pragma unroll
    for (int mt = 0; mt < 3; ++mt) {
        #pragma unroll
        for (int reg = 0; reg < 4; ++reg) {
            const int m = mh*48 + mt*16 + quad*4 + reg;
            const float lse = lseS[m];
            const size_t base = ((size_t)db * HEADS + m) * RELP;
            #pragma unroll
            for (int nt = 0; nt < 4; ++nt)
                out[base + 1 + nh*64 + nt*16 + ln15] = acc[mt][nt][reg] + bpv[nt] - lse;
            if (nh == 0 && ln15 == 0) out[base] = -lse;
        }
    }
}

extern "C" void kernel_launch(void* const* d_in, const int* in_sizes, int n_in,
                              void* d_out, int out_size, void* d_ws, size_t ws_size,
                              hipStream_t stream) {
    const float* outs  = (const float*)d_in[0];
    const float* graph = (const float*)d_in[1];
    const float* Wt    = (const float*)d_in[2];
    const float* bt    = (const float*)d_in[3];
    const float* Wp    = (const float*)d_in[4];
    const float* bp    = (const float*)d_in[5];
    float* out = (float*)d_out;

    // Workspace: 4,849,664 B (WtH eliminated; Wt cast inline in proj).
    float* P1           = (float*)d_ws;                     // [1536][512] f32   (3 MB)
    unsigned short* P2H = (unsigned short*)(P1 + 786432);   // [1536][512] fp16  (1.5 MB)
    unsigned short* WpH = P2H + 786432;                     // [128][512]  fp16  (128 KB)

    proj_kernel<<<dim3(DIM/64, (DEP*BSZ)/32, 2), 256, 0, stream>>>(
        outs, graph, Wt, bt, Wp, P1, P2H, WpH);
    fused_kernel<<<DEP*BSZ, 256, 0, stream>>>(P1, P2H, WpH, bp, out);
}